// Round 11
// baseline (908.592 us; speedup 1.0000x reference)
//
#include <hip/hip_runtime.h>

typedef float v2f __attribute__((ext_vector_type(2)));
typedef float v4f __attribute__((ext_vector_type(4)));

#define BATCH 2048
#define TSEQ 512
#define FUT 64
#define TOUT (TSEQ + FUT)   // 576
#define HID 50

// Block = 256 threads = 4 waves = ONE batch row. Wave g owns gate g:
//   wave0 = i, wave1 = f, wave2 = g(tanh), wave3 = o.
// Per-lane weights: ONE 50-float W_hh row = 25 v2f = 50 VGPRs (small enough
// to stay in arch VGPRs under the 128/wave budget of launch_bounds(256,4)).
// Gates exchanged via LDS; c/h update done redundantly by all 4 waves.

__device__ __forceinline__ float rcp_f(float x) { return __builtin_amdgcn_rcpf(x); }
__device__ __forceinline__ float sigm(float x)  { return rcp_f(1.f + __expf(-x)); }
__device__ __forceinline__ float tanh_f(float x){ return 1.f - 2.f * rcp_f(__expf(2.f * x) + 1.f); }

// packed 2xf32 FMA: acc = a*b + acc  (VOP3P v_pk_fma_f32)
__device__ __forceinline__ void pkfma(v2f& acc, v2f a, v2f b) {
  asm("v_pk_fma_f32 %0, %1, %2, %0" : "+v"(acc) : "v"(a), "v"(b));
}

__global__ __launch_bounds__(256, 4) void lstm_seq_kernel(
    const float* __restrict__ x,      // [B, T]
    const float* __restrict__ W_ih,   // [200, 1]
    const float* __restrict__ W_hh,   // [200, 50]
    const float* __restrict__ b_ih,   // [200]
    const float* __restrict__ b_hh,   // [200]
    const float* __restrict__ W_out,  // [1, 50]
    const float* __restrict__ b_out,  // [1]
    float* __restrict__ out)          // [B, 576]
{
  __shared__ float sH[64];       // h broadcast (lanes >=50 hold 0)
  __shared__ float sG[4][64];    // per-gate activated values, lane-indexed
  __shared__ float sOut[1];      // prediction feedback for the future phase
  __shared__ float sx[TSEQ];     // this row's input

  const int tid  = threadIdx.x;
  const int wv   = tid >> 6;            // gate index 0..3
  const int lane = tid & 63;
  const int row  = blockIdx.x;

  for (int i = tid; i < TSEQ; i += 256) sx[i] = x[row * TSEQ + i];
  if (tid < 64) sH[tid] = 0.f;

  const bool act = (lane < HID);
  const int  kk  = act ? lane : 0;
  const int  r   = wv * HID + kk;       // this wave's gate row for lane kk

  // one-time weight load: row r of W_hh (200B stride -> 8B-aligned v2f)
  v2f w[25];
  {
    const v2f* p = (const v2f*)(W_hh + r * HID);
    #pragma unroll
    for (int j = 0; j < 25; ++j) w[j] = p[j];
  }
  const float bg0 = b_ih[r] + b_hh[r];
  const float wx  = W_ih[r];
  const float wout = act ? W_out[kk] : 0.f;
  const float bout = b_out[0];

  float c = 0.f;                        // per-lane cell state (all 4 waves keep
                                        // identical redundant copies)
  float* orow = out + (size_t)row * TOUT;
  const v4f* sH4 = (const v4f*)sH;
  const v2f* sH2 = (const v2f*)sH;

  __syncthreads();

  auto step = [&](float xv, int t) {
    // ---- phase A: this wave's gate pre-activation over K=50 ----
    v2f a2 = {fmaf(xv, wx, bg0), 0.f};
    v2f a2b = {0.f, 0.f};               // second chain to shorten dep path
    #pragma unroll
    for (int q = 0; q < 6; ++q) {       // m = 0..23
      v4f h4 = sH4[q];
      v2f ha = {h4.x, h4.y}, hb = {h4.z, h4.w};
      pkfma(a2,  w[2 * q],     ha);
      pkfma(a2b, w[2 * q + 1], hb);
    }
    #pragma unroll
    for (int q = 6; q < 12; ++q) {      // m = 24..47
      v4f h4 = sH4[q];
      v2f ha = {h4.x, h4.y}, hb = {h4.z, h4.w};
      pkfma(a2,  w[2 * q],     ha);
      pkfma(a2b, w[2 * q + 1], hb);
    }
    { v2f ht = sH2[24]; pkfma(a2, w[24], ht); }      // m = 48,49
    const float pre = (a2.x + a2b.x) + (a2.y + a2b.y);
    const float g   = (wv == 2) ? tanh_f(pre) : sigm(pre);
    sG[wv][lane] = g;                   // lane-indexed: no clobber from idle lanes
    __syncthreads();                    // barrier 1: all gates published

    // ---- phase B: redundant c/h update on every wave ----
    const float gi = sG[0][lane];
    const float gf = sG[1][lane];
    const float gg = sG[2][lane];
    const float go = sG[3][lane];
    c = fmaf(gf, c, gi * gg);           // junk in lanes >=50, masked below
    const float h = act ? go * tanh_f(c) : 0.f;
    if (wv == 0) {
      sH[lane] = h;                     // publish h for next step
      float p = h * wout;               // out_t = sum h[k] W_out[k] + b
      p += __shfl_xor(p, 1);
      p += __shfl_xor(p, 2);
      p += __shfl_xor(p, 4);
      p += __shfl_xor(p, 8);
      p += __shfl_xor(p, 16);
      p += __shfl_xor(p, 32);
      const float ot = p + bout;
      if (lane == 0) { orow[t] = ot; sOut[0] = ot; }
    }
    __syncthreads();                    // barrier 2: sH/sOut ready
  };

  #pragma unroll 1
  for (int t = 0; t < TSEQ; ++t) step(sx[t], t);       // teacher-forced
  #pragma unroll 1
  for (int t = TSEQ; t < TOUT; ++t) step(sOut[0], t);  // autoregressive
}

extern "C" void kernel_launch(void* const* d_in, const int* in_sizes, int n_in,
                              void* d_out, int out_size, void* d_ws, size_t ws_size,
                              hipStream_t stream) {
  const float* x     = (const float*)d_in[0];
  const float* W_ih  = (const float*)d_in[1];
  const float* W_hh  = (const float*)d_in[2];
  const float* b_ih  = (const float*)d_in[3];
  const float* b_hh  = (const float*)d_in[4];
  const float* W_out = (const float*)d_in[5];
  const float* b_out = (const float*)d_in[6];
  float* out = (float*)d_out;

  lstm_seq_kernel<<<BATCH, 256, 0, stream>>>(
      x, W_ih, W_hh, b_ih, b_hh, W_out, b_out, out);
}

// Round 14
// 584.776 us; speedup vs baseline: 1.5537x; 1.5537x over previous
//
#include <hip/hip_runtime.h>

typedef float v2f __attribute__((ext_vector_type(2)));
typedef float v4f __attribute__((ext_vector_type(4)));

#define BATCH 2048
#define TSEQ 512
#define FUT 64
#define TOUT (TSEQ + FUT)   // 576
#define HID 50
#define RPB 4               // 4 waves per block, 1 batch row per wave

// Structure (best measured: R5): ONE wave per batch row, zero barriers in the
// sequential loop. New in R12: the autoregressive feedback out_t -> x_{t+1}
// is eliminated by folding the rank-1 update W_ih (x) W_out into the
// register-resident weights at t==TSEQ (out_t is linear in h_t):
//   gates_{t+1} = (W_hh + W_ih*W_out^T) h_t + (b + W_ih*b_out)
// The per-step shuffle-reduction now ONLY feeds the out[t] store (dead-end
// dataflow, latency hidden under the next step's matvec).

__device__ __forceinline__ float rcp_f(float x) { return __builtin_amdgcn_rcpf(x); }
__device__ __forceinline__ float sigm(float x)  { return rcp_f(1.f + __expf(-x)); }
__device__ __forceinline__ float tanh_f(float x){ return 1.f - 2.f * rcp_f(__expf(2.f * x) + 1.f); }

// packed 2xf32 FMA: acc = a*b + acc  (VOP3P v_pk_fma_f32)
__device__ __forceinline__ void pkfma(v2f& acc, v2f a, v2f b) {
  asm("v_pk_fma_f32 %0, %1, %2, %0" : "+v"(acc) : "v"(a), "v"(b));
}

__global__ __launch_bounds__(256, 2) void lstm_seq_kernel(
    const float* __restrict__ x,      // [B, T]
    const float* __restrict__ W_ih,   // [200, 1]
    const float* __restrict__ W_hh,   // [200, 50]
    const float* __restrict__ b_ih,   // [200]
    const float* __restrict__ b_hh,   // [200]
    const float* __restrict__ W_out,  // [1, 50]
    const float* __restrict__ b_out,  // [1]
    float* __restrict__ out)          // [B, 576]
{
  __shared__ float sx[RPB][TSEQ];   // 8 KB: input rows for this block
  __shared__ float sH[RPB][64];     // per-wave h broadcast (wave-private row)

  const int tid  = threadIdx.x;
  const int wv   = tid >> 6;
  const int lane = tid & 63;
  const int row  = blockIdx.x * RPB + wv;

  for (int i = tid; i < RPB * TSEQ; i += 256)
    ((float*)sx)[i] = x[blockIdx.x * RPB * TSEQ + i];
  if (tid < RPB * 64) ((float*)sH)[tid] = 0.f;
  __syncthreads();                  // the ONLY barrier

  const bool act = (lane < HID);
  const int  kk  = act ? lane : 0;

  // per-lane weights: rows {kk, kk+50, kk+100, kk+150} of W_hh (one-time load)
  v2f wi[25], wf[25], wg[25], wo[25];
  {
    const v2f* r0 = (const v2f*)(W_hh + (0 * HID + kk) * HID);
    const v2f* r1 = (const v2f*)(W_hh + (1 * HID + kk) * HID);
    const v2f* r2 = (const v2f*)(W_hh + (2 * HID + kk) * HID);
    const v2f* r3 = (const v2f*)(W_hh + (3 * HID + kk) * HID);
    #pragma unroll
    for (int j = 0; j < 25; ++j) { wi[j] = r0[j]; wf[j] = r1[j]; wg[j] = r2[j]; wo[j] = r3[j]; }
  }
  float bi = b_ih[0 * HID + kk] + b_hh[0 * HID + kk];
  float bf = b_ih[1 * HID + kk] + b_hh[1 * HID + kk];
  float bg = b_ih[2 * HID + kk] + b_hh[2 * HID + kk];
  float bo = b_ih[3 * HID + kk] + b_hh[3 * HID + kk];
  const float wxi = W_ih[0 * HID + kk];
  const float wxf = W_ih[1 * HID + kk];
  const float wxg = W_ih[2 * HID + kk];
  const float wxo = W_ih[3 * HID + kk];
  const float wout = act ? W_out[kk] : 0.f;
  const float bout = b_out[0];

  float h = 0.f, c = 0.f;
  float* orow = out + (size_t)row * TOUT;
  const v4f* sH4 = (const v4f*)sH[wv];
  const v2f* sH2 = (const v2f*)sH[wv];

  #pragma unroll 1
  for (int t = 0; t < TOUT; ++t) {
    if (t == TSEQ) {
      // one-time rank-1 fold: W += W_ih (x) W_out ; b += W_ih * b_out.
      // After this the autoregressive input term is inside the weights.
      const v2f* wo2 = (const v2f*)W_out;
      const v2f xi = {wxi, wxi}, xf = {wxf, wxf}, xg = {wxg, wxg}, xo = {wxo, wxo};
      #pragma unroll
      for (int j = 0; j < 25; ++j) {
        const v2f wv_ = wo2[j];
        pkfma(wi[j], xi, wv_);
        pkfma(wf[j], xf, wv_);
        pkfma(wg[j], xg, wv_);
        pkfma(wo[j], xo, wv_);
      }
      bi = fmaf(wxi, bout, bi);
      bf = fmaf(wxf, bout, bf);
      bg = fmaf(wxg, bout, bg);
      bo = fmaf(wxo, bout, bo);
    }
    const float xv = (t < TSEQ) ? sx[wv][t] : 0.f;   // future phase: folded in

    sH[wv][lane] = h;                 // wave-private; HW-ordered vs reads below

    v2f ai = {fmaf(xv, wxi, bi), 0.f};
    v2f af = {fmaf(xv, wxf, bf), 0.f};
    v2f ag = {fmaf(xv, wxg, bg), 0.f};
    v2f ao = {fmaf(xv, wxo, bo), 0.f};
    #pragma unroll
    for (int q = 0; q < 12; ++q) {    // m = 0..47, uniform b128 broadcast reads
      const v4f h4 = sH4[q];
      const v2f ha = {h4.x, h4.y}, hb = {h4.z, h4.w};
      pkfma(ai, wi[2 * q], ha); pkfma(ai, wi[2 * q + 1], hb);
      pkfma(af, wf[2 * q], ha); pkfma(af, wf[2 * q + 1], hb);
      pkfma(ag, wg[2 * q], ha); pkfma(ag, wg[2 * q + 1], hb);
      pkfma(ao, wo[2 * q], ha); pkfma(ao, wo[2 * q + 1], hb);
    }
    { const v2f ht = sH2[24];         // m = 48,49
      pkfma(ai, wi[24], ht); pkfma(af, wf[24], ht);
      pkfma(ag, wg[24], ht); pkfma(ao, wo[24], ht); }

    const float gi = sigm(ai.x + ai.y);
    const float gf = sigm(af.x + af.y);
    const float gg = tanh_f(ag.x + ag.y);
    const float go = sigm(ao.x + ao.y);
    c = fmaf(gf, c, gi * gg);
    h = act ? go * tanh_f(c) : 0.f;

    // out[t] = sum_k h[k] W_out[k] + b_out — DEAD-END dataflow: nothing in the
    // next iteration reads p, so this chain overlaps the next step's matvec.
    float p = h * wout;
    p += __shfl_xor(p, 1);
    p += __shfl_xor(p, 2);
    p += __shfl_xor(p, 4);
    p += __shfl_xor(p, 8);
    p += __shfl_xor(p, 16);
    p += __shfl_xor(p, 32);
    if (lane == 0) orow[t] = p + bout;
  }
}

extern "C" void kernel_launch(void* const* d_in, const int* in_sizes, int n_in,
                              void* d_out, int out_size, void* d_ws, size_t ws_size,
                              hipStream_t stream) {
  const float* x     = (const float*)d_in[0];
  const float* W_ih  = (const float*)d_in[1];
  const float* W_hh  = (const float*)d_in[2];
  const float* b_ih  = (const float*)d_in[3];
  const float* b_hh  = (const float*)d_in[4];
  const float* W_out = (const float*)d_in[5];
  const float* b_out = (const float*)d_in[6];
  float* out = (float*)d_out;

  lstm_seq_kernel<<<BATCH / RPB, 256, 0, stream>>>(
      x, W_ih, W_hh, b_ih, b_hh, W_out, b_out, out);
}